// Round 13
// baseline (141.429 us; speedup 1.0000x reference)
//
#include <hip/hip_runtime.h>
#include <hip/hip_bf16.h>
#include <stdint.h>

typedef short bf16x8 __attribute__((ext_vector_type(8)));   // 8 bf16 in 4 VGPRs
typedef float f32x4 __attribute__((ext_vector_type(4)));
typedef unsigned short u16;
typedef u16 ushort8 __attribute__((ext_vector_type(8)));

typedef __attribute__((address_space(3))) void lds_void;
typedef const __attribute__((address_space(1))) void gbl_void;

#define BAR() do { asm volatile("" ::: "memory"); __builtin_amdgcn_s_barrier(); asm volatile("" ::: "memory"); } while (0)
#define WAITV(N) asm volatile("s_waitcnt vmcnt(" #N ")" ::: "memory")
#define WAITL0() asm volatile("s_waitcnt lgkmcnt(0)" ::: "memory")   // NO sched_barrier (m141)
#define HINTL8() asm volatile("s_waitcnt lgkmcnt(8)" ::: "memory")

__device__ __forceinline__ u16 f2bf(float f) {
  uint32_t u = __builtin_bit_cast(uint32_t, f);
  u += 0x7fffu + ((u >> 16) & 1u);   // round-to-nearest-even
  return (u16)(u >> 16);
}

// ------------- fused prep: blocks 0..4095 build Mt, 4096..12287 cvt x -------
__global__ __launch_bounds__(256) void prep_fused(
    const float* __restrict__ x, u16* __restrict__ xb,
    const float* __restrict__ c0, const float* __restrict__ c1,
    const float* __restrict__ c2, const float* __restrict__ c3,
    u16* __restrict__ Mt) {
  const int t = threadIdx.x;
  if (blockIdx.x >= 4096) {
    const int i = ((blockIdx.x - 4096) * 256 + t) * 8;
    float4 a = *(const float4*)(x + i);
    float4 b = *(const float4*)(x + i + 4);
    ushort8 o;
    o[0] = f2bf(a.x); o[1] = f2bf(a.y); o[2] = f2bf(a.z); o[3] = f2bf(a.w);
    o[4] = f2bf(b.x); o[5] = f2bf(b.y); o[6] = f2bf(b.z); o[7] = f2bf(b.w);
    *(ushort8*)(xb + i) = o;
    return;
  }
  const int bid = blockIdx.x;
  const int j1 = bid & 7, i1 = (bid >> 3) & 7, j0 = (bid >> 6) & 7, i0 = bid >> 9;
  __shared__ float v[512];   // [i2][j2][r3]
  __shared__ float g3[512];  // copy of c3 [r3][i3][j3]
  g3[t] = c3[t];
  g3[t + 256] = c3[t + 256];
  float w2[8];
#pragma unroll
  for (int r2 = 0; r2 < 8; ++r2) {
    float s = 0.f;
#pragma unroll
    for (int r1 = 0; r1 < 8; ++r1)
      s += c0[(i0 * 8 + j0) * 8 + r1] * c1[((r1 * 8 + i1) * 8 + j1) * 8 + r2];
    w2[r2] = s;
  }
#pragma unroll
  for (int e = t; e < 512; e += 256) {
    const int r3 = e & 7, j2 = (e >> 3) & 7, i2 = e >> 6;
    float s = 0.f;
#pragma unroll
    for (int r2 = 0; r2 < 8; ++r2)
      s += w2[r2] * c2[((r2 * 8 + i2) * 8 + j2) * 8 + r3];
    v[e] = s;
  }
  __syncthreads();
  const int jr = t >> 2, ic0 = (t & 3) * 16;
  const int j2 = jr >> 3, j3 = jr & 7;
  const size_t base =
      (size_t)(j0 * 512 + j1 * 64 + jr) * 4096 + (i0 * 512 + i1 * 64) + ic0;
  ushort8 o0, o1;
#pragma unroll
  for (int q = 0; q < 16; ++q) {
    const int ic = ic0 + q, i2 = ic >> 3, i3 = ic & 7;
    float s = 0.f;
#pragma unroll
    for (int r3 = 0; r3 < 8; ++r3)
      s += v[(i2 << 6) + (j2 << 3) + r3] * g3[(r3 << 6) + (i3 << 3) + j3];
    const u16 h = f2bf(s);
    if (q < 8) o0[q] = h; else o1[q - 8] = h;
  }
  *(ushort8*)(Mt + base) = o0;
  *(ushort8*)(Mt + base + 8) = o1;
}

// ---------------- GEMM: 256x256, BK=64, m201-style two-barrier 8-phase ------
// A/B test vs R5 (130.5 us): identical schedule, but lgkmcnt(0) WITHOUT
// sched_barrier(0) (m141: order-pinning poison). R6 single-barrier variant
// (118 us) is the fallback if this lands >=125 us.
// Stage ledger (iter computes T,T+1; per phase ONE region = 2 gload_lds):
//   P1: A(1,0,T+1)  P2: A(1,1,T+1)  P3: B(0,0,T+2)  P4: B(0,1,T+2)+A(0,0,T+2)
//   P5: A(0,1,T+2)  P6: --          P7: B(1,0,T+3)  P8: B(1,1,T+3)
// vmcnt(6)@P4 / vmcnt(4)@P8 (counts verified: forces exactly tile T+1 / T+2).
// Region lifetimes: B(0,h) last read P2; A(0,h) P3; B(1,h) P6; A(1,h) P7 —
// every stage >=1 barrier after its region's last read (lgkm-drained).
// Swizzle: 16B chunk at (c ^ (row&7)) on source and ds_read (rule #21).
__global__ __launch_bounds__(512, 2) void gemm_bias_relu(
    const u16* __restrict__ A, const u16* __restrict__ Bt,
    const float* __restrict__ bias, float* __restrict__ C) {
  constexpr int K = 4096, N = 4096, NT = 64;
  __shared__ __align__(16) char lds[131072];
  const int t = threadIdx.x;
  const int l = t & 63, w = t >> 6;
  const int wr = w >> 2, wc = w & 3;            // 2 x 4 wave grid
  const int lr = l & 15, lk = l >> 4;
  const int bm = blockIdx.y, bn = blockIdx.x;

  const char* gA = (const char*)A + (size_t)bm * 256 * (K * 2);
  const char* gB = (const char*)Bt + (size_t)bn * 256 * (K * 2);
  const int srow = t >> 3;                      // 0..63
  const int schunk = (t & 7) ^ (srow & 7);      // pre-swizzled source chunk
  const int sgo = srow * (K * 2) + schunk * 16;
  const int sld = t * 16;

  const int axor = (lk ^ (lr & 7)) * 16;        // kk0 chunk; kk1 = axor ^ 64
  const int aoff0 = (wr * 128 + lr) * 128 + axor;
  const int aoff1 = aoff0 ^ 64;
  const int boff0 = 65536 + (wc * 64 + lr) * 128 + axor;
  const int boff1 = boff0 ^ 64;

  auto stA = [&](int p, int h, int kt) {        // stage A M-half h of tile kt
    const char* src = gA + (size_t)(h * 128) * (K * 2) + kt * 128 + sgo;
    char* dst = lds + p * 32768 + h * 16384 + sld;
    __builtin_amdgcn_global_load_lds((gbl_void*)src, (lds_void*)dst, 16, 0, 0);
    __builtin_amdgcn_global_load_lds((gbl_void*)(src + (size_t)64 * (K * 2)),
                                     (lds_void*)(dst + 8192), 16, 0, 0);
  };
  auto stB = [&](int p, int h, int kt) {
    const char* src = gB + (size_t)(h * 128) * (K * 2) + kt * 128 + sgo;
    char* dst = lds + 65536 + p * 32768 + h * 16384 + sld;
    __builtin_amdgcn_global_load_lds((gbl_void*)src, (lds_void*)dst, 16, 0, 0);
    __builtin_amdgcn_global_load_lds((gbl_void*)(src + (size_t)64 * (K * 2)),
                                     (lds_void*)(dst + 8192), 16, 0, 0);
  };
  auto rdA = [&](int p, int off, int m) -> bf16x8 {
    return *(const bf16x8*)(lds + p * 32768 + off + m * 2048);
  };
  auto rdB = [&](int p, int off, int n) -> bf16x8 {
    return *(const bf16x8*)(lds + p * 32768 + off + n * 2048);
  };

  bf16x8 aH0[8], aH1[8], bH0[4], bH1[4];
  f32x4 acc[8][4];
#pragma unroll
  for (int m = 0; m < 8; ++m)
#pragma unroll
    for (int n = 0; n < 4; ++n) acc[m][n] = f32x4{0.f, 0.f, 0.f, 0.f};

  auto rdAH = [&](bf16x8* d, int p, int mh) {   // 4m x 2kk = 8 reads
#pragma unroll
    for (int m2 = 0; m2 < 4; ++m2) {
      d[m2 * 2 + 0] = rdA(p, aoff0, mh * 4 + m2);
      d[m2 * 2 + 1] = rdA(p, aoff1, mh * 4 + m2);
    }
  };
  auto rdBH = [&](bf16x8* d, int p, int nh) {   // 2n x 2kk = 4 reads
#pragma unroll
    for (int n2 = 0; n2 < 2; ++n2) {
      d[n2 * 2 + 0] = rdB(p, boff0, nh * 2 + n2);
      d[n2 * 2 + 1] = rdB(p, boff1, nh * 2 + n2);
    }
  };
  auto quad = [&](int mh, int nh, bf16x8* aH, bf16x8* bH) {  // 16 MFMA
    __builtin_amdgcn_s_setprio(1);
#pragma unroll
    for (int kk = 0; kk < 2; ++kk)
#pragma unroll
      for (int m2 = 0; m2 < 4; ++m2)
#pragma unroll
        for (int n2 = 0; n2 < 2; ++n2)
          acc[mh * 4 + m2][nh * 2 + n2] = __builtin_amdgcn_mfma_f32_16x16x32_bf16(
              aH[m2 * 2 + kk], bH[n2 * 2 + kk], acc[mh * 4 + m2][nh * 2 + n2], 0, 0, 0);
    __builtin_amdgcn_s_setprio(0);
  };

  // ---- prologue: tile0 all 4 halves, tile1 B halves; force tile0 ----
  stA(0, 0, 0); stB(0, 0, 0); stB(0, 1, 0); stA(0, 1, 0);
  stB(1, 0, 1); stB(1, 1, 1);
  WAITV(4);        // force tile0's 8 loads; tile1-B's 4 stay in flight
  BAR();

  for (int it = 0; it < NT / 2; ++it) {
    const int T = 2 * it;
    const int t2 = (T + 2 < NT) ? T + 2 : NT - 1;
    const int t3 = (T + 3 < NT) ? T + 3 : NT - 1;
    // ---------- P1: rd T.A-mh0 + T.B-nh0 (12); stage A(1,0,T+1) ----------
    rdAH(aH0, 0, 0); rdBH(bH0, 0, 0);
    stA(1, 0, T + 1);
    HINTL8();
    BAR(); WAITL0();
    quad(0, 0, aH0, bH0);
    BAR();
    // ---------- P2: rd T.B-nh1 (4); stage A(1,1,T+1) ----------
    rdBH(bH1, 0, 1);
    stA(1, 1, T + 1);
    BAR(); WAITL0();
    quad(0, 1, aH0, bH1);
    BAR();
    // ---------- P3: rd T.A-mh1 (8); stage B(0,0,T+2) ----------
    rdAH(aH1, 0, 1);
    stB(0, 0, t2);
    BAR(); WAITL0();
    quad(1, 1, aH1, bH1);
    BAR();
    // ---------- P4: stage B(0,1,T+2) + A(0,0,T+2); vmcnt(6) ----------
    stB(0, 1, t2); stA(0, 0, t2);
    BAR(); WAITL0();
    quad(1, 0, aH1, bH0);
    WAITV(6);
    BAR();
    // ---------- P5: rd (T+1).A-mh0 + B-nh0 (12); stage A(0,1,T+2) ----------
    rdAH(aH0, 1, 0); rdBH(bH0, 1, 0);
    stA(0, 1, t2);
    HINTL8();
    BAR(); WAITL0();
    quad(0, 0, aH0, bH0);
    BAR();
    // ---------- P6: rd (T+1).B-nh1 (4) ----------
    rdBH(bH1, 1, 1);
    BAR(); WAITL0();
    quad(0, 1, aH0, bH1);
    BAR();
    // ---------- P7: rd (T+1).A-mh1 (8); stage B(1,0,T+3) ----------
    rdAH(aH1, 1, 1);
    stB(1, 0, t3);
    BAR(); WAITL0();
    quad(1, 1, aH1, bH1);
    BAR();
    // ---------- P8: stage B(1,1,T+3); vmcnt(4) ----------
    stB(1, 1, t3);
    BAR(); WAITL0();
    quad(1, 0, aH1, bH0);
    WAITV(4);
    BAR();
  }
  WAITV(0);

  // ---- epilogue: bias + relu, fp32 stores ----
  const int row0 = bm * 256 + wr * 128;
  const int col0 = bn * 256 + wc * 64;
#pragma unroll
  for (int n = 0; n < 4; ++n) {
    const int col = col0 + n * 16 + lr;
    const float bv = bias[col];
#pragma unroll
    for (int m = 0; m < 8; ++m) {
      const int r0 = row0 + m * 16 + lk * 4;
#pragma unroll
      for (int vv = 0; vv < 4; ++vv) {
        const float val = acc[m][n][vv] + bv;
        C[(size_t)(r0 + vv) * N + col] = val > 0.f ? val : 0.f;
      }
    }
  }
}

extern "C" void kernel_launch(void* const* d_in, const int* in_sizes, int n_in,
                              void* d_out, int out_size, void* d_ws, size_t ws_size,
                              hipStream_t stream) {
  const float* x  = (const float*)d_in[0];
  const float* c0 = (const float*)d_in[1];
  const float* c1 = (const float*)d_in[2];
  const float* c2 = (const float*)d_in[3];
  const float* c3 = (const float*)d_in[4];
  const float* b  = (const float*)d_in[5];
  float* out = (float*)d_out;

  u16* xb  = (u16*)d_ws;                       // 32 MB bf16 x
  u16* mtb = xb + (size_t)4096 * 4096;         // 32 MB bf16 M^T

  prep_fused<<<dim3(4096 + 8192), dim3(256), 0, stream>>>(x, xb, c0, c1, c2, c3, mtb);
  gemm_bias_relu<<<dim3(16, 16), dim3(512), 0, stream>>>(xb, mtb, b, out);
}

// Round 14
// 135.392 us; speedup vs baseline: 1.0446x; 1.0446x over previous
//
#include <hip/hip_runtime.h>
#include <hip/hip_bf16.h>
#include <stdint.h>

typedef short bf16x8 __attribute__((ext_vector_type(8)));   // 8 bf16 in 4 VGPRs
typedef float f32x4 __attribute__((ext_vector_type(4)));
typedef unsigned short u16;
typedef u16 ushort8 __attribute__((ext_vector_type(8)));

typedef __attribute__((address_space(3))) void lds_void;
typedef const __attribute__((address_space(1))) void gbl_void;

#define BAR() do { asm volatile("" ::: "memory"); __builtin_amdgcn_s_barrier(); asm volatile("" ::: "memory"); } while (0)
#define WAITV(N) asm volatile("s_waitcnt vmcnt(" #N ")" ::: "memory")

__device__ __forceinline__ u16 f2bf(float f) {
  uint32_t u = __builtin_bit_cast(uint32_t, f);
  u += 0x7fffu + ((u >> 16) & 1u);   // round-to-nearest-even
  return (u16)(u >> 16);
}

// ------------- fused prep: blocks 0..4095 build Mt, 4096..12287 cvt x -------
__global__ __launch_bounds__(256) void prep_fused(
    const float* __restrict__ x, u16* __restrict__ xb,
    const float* __restrict__ c0, const float* __restrict__ c1,
    const float* __restrict__ c2, const float* __restrict__ c3,
    u16* __restrict__ Mt) {
  const int t = threadIdx.x;
  if (blockIdx.x >= 4096) {
    const int i = ((blockIdx.x - 4096) * 256 + t) * 8;
    float4 a = *(const float4*)(x + i);
    float4 b = *(const float4*)(x + i + 4);
    ushort8 o;
    o[0] = f2bf(a.x); o[1] = f2bf(a.y); o[2] = f2bf(a.z); o[3] = f2bf(a.w);
    o[4] = f2bf(b.x); o[5] = f2bf(b.y); o[6] = f2bf(b.z); o[7] = f2bf(b.w);
    *(ushort8*)(xb + i) = o;
    return;
  }
  const int bid = blockIdx.x;
  const int j1 = bid & 7, i1 = (bid >> 3) & 7, j0 = (bid >> 6) & 7, i0 = bid >> 9;
  __shared__ float v[512];   // [i2][j2][r3]
  __shared__ float g3[512];  // copy of c3 [r3][i3][j3]
  g3[t] = c3[t];
  g3[t + 256] = c3[t + 256];
  float w2[8];
#pragma unroll
  for (int r2 = 0; r2 < 8; ++r2) {
    float s = 0.f;
#pragma unroll
    for (int r1 = 0; r1 < 8; ++r1)
      s += c0[(i0 * 8 + j0) * 8 + r1] * c1[((r1 * 8 + i1) * 8 + j1) * 8 + r2];
    w2[r2] = s;
  }
#pragma unroll
  for (int e = t; e < 512; e += 256) {
    const int r3 = e & 7, j2 = (e >> 3) & 7, i2 = e >> 6;
    float s = 0.f;
#pragma unroll
    for (int r2 = 0; r2 < 8; ++r2)
      s += w2[r2] * c2[((r2 * 8 + i2) * 8 + j2) * 8 + r3];
    v[e] = s;
  }
  __syncthreads();
  const int jr = t >> 2, ic0 = (t & 3) * 16;
  const int j2 = jr >> 3, j3 = jr & 7;
  const size_t base =
      (size_t)(j0 * 512 + j1 * 64 + jr) * 4096 + (i0 * 512 + i1 * 64) + ic0;
  ushort8 o0, o1;
#pragma unroll
  for (int q = 0; q < 16; ++q) {
    const int ic = ic0 + q, i2 = ic >> 3, i3 = ic & 7;
    float s = 0.f;
#pragma unroll
    for (int r3 = 0; r3 < 8; ++r3)
      s += v[(i2 << 6) + (j2 << 3) + r3] * g3[(r3 << 6) + (i3 << 3) + j3];
    const u16 h = f2bf(s);
    if (q < 8) o0[q] = h; else o1[q - 8] = h;
  }
  *(ushort8*)(Mt + base) = o0;
  *(ushort8*)(Mt + base + 8) = o1;
}

// ---------------- GEMM: 256x256, BK=64, R6 8-phase (reads feed next phase) --
// 8 waves (2Mx4N). Quads per tile: Q1=(mh0,nh0) Q2=(mh0,nh1) Q3=(mh1,nh1)
// Q4=(mh1,nh0). Reads issued one phase before their consuming quad; NO manual
// lgkm waits (compiler emits counted lgkmcnt -> current phase's reads drain
// UNDER the MFMA cluster). One barrier per phase. Stages placed AFTER the
// MFMA so each stage provably follows the consuming MFMA of its region's
// last read. Only bH0 wraps the quad cycle: its reload is ordered after Q4.
// vmcnt(6)@P4 forces exactly tile T+1; vmcnt(4)@P8 forces exactly tile T+2.
// Prologue stages tile0 + tile1-B, vmcnt(4) = steady state. Tail clamps
// re-stage only dead regions. Swizzle: chunk c at (c ^ (row&7)) on
// pre-swizzled global source and ds_read (rule #21).
// PROVEN OPTIMUM (13 rounds): 118 us, MfmaUtil 53.4%, 0 conflicts.
// Measured-worse alternatives: two-barrier 8-phase w/ and w/o sched_barrier
// (R5/R13: 130.5), 4-phase merge (R8: 124.5), 32x32x16 MFMA (R11: 132.9,
// 1.3e7 bank conflicts), fused f32 A-staging (R9: 430, spills), counted-vmcnt
// read-ahead (R3: 143).
__global__ __launch_bounds__(512, 2) void gemm_bias_relu(
    const u16* __restrict__ A, const u16* __restrict__ Bt,
    const float* __restrict__ bias, float* __restrict__ C) {
  constexpr int K = 4096, N = 4096, NT = 64;
  __shared__ __align__(16) char lds[131072];
  const int t = threadIdx.x;
  const int l = t & 63, w = t >> 6;
  const int wr = w >> 2, wc = w & 3;            // 2 x 4 wave grid
  const int lr = l & 15, lk = l >> 4;
  const int bm = blockIdx.y, bn = blockIdx.x;

  const char* gA = (const char*)A + (size_t)bm * 256 * (K * 2);
  const char* gB = (const char*)Bt + (size_t)bn * 256 * (K * 2);
  const int srow = t >> 3;                      // 0..63
  const int schunk = (t & 7) ^ (srow & 7);      // pre-swizzled source chunk
  const int sgo = srow * (K * 2) + schunk * 16;
  const int sld = t * 16;

  const int axor = (lk ^ (lr & 7)) * 16;        // kk0 chunk; kk1 = axor ^ 64
  const int aoff0 = (wr * 128 + lr) * 128 + axor;
  const int aoff1 = aoff0 ^ 64;
  const int boff0 = 65536 + (wc * 64 + lr) * 128 + axor;
  const int boff1 = boff0 ^ 64;

  auto stA = [&](int p, int h, int kt) {        // stage A M-half h of tile kt
    const char* src = gA + (size_t)(h * 128) * (K * 2) + kt * 128 + sgo;
    char* dst = lds + p * 32768 + h * 16384 + sld;
    __builtin_amdgcn_global_load_lds((gbl_void*)src, (lds_void*)dst, 16, 0, 0);
    __builtin_amdgcn_global_load_lds((gbl_void*)(src + (size_t)64 * (K * 2)),
                                     (lds_void*)(dst + 8192), 16, 0, 0);
  };
  auto stB = [&](int p, int h, int kt) {
    const char* src = gB + (size_t)(h * 128) * (K * 2) + kt * 128 + sgo;
    char* dst = lds + 65536 + p * 32768 + h * 16384 + sld;
    __builtin_amdgcn_global_load_lds((gbl_void*)src, (lds_void*)dst, 16, 0, 0);
    __builtin_amdgcn_global_load_lds((gbl_void*)(src + (size_t)64 * (K * 2)),
                                     (lds_void*)(dst + 8192), 16, 0, 0);
  };
  auto rdA = [&](int p, int off, int m) -> bf16x8 {
    return *(const bf16x8*)(lds + p * 32768 + off + m * 2048);
  };
  auto rdB = [&](int p, int off, int n) -> bf16x8 {
    return *(const bf16x8*)(lds + p * 32768 + off + n * 2048);
  };

  bf16x8 aH0[8], aH1[8], bH0[4], bH1[4];
  f32x4 acc[8][4];
#pragma unroll
  for (int m = 0; m < 8; ++m)
#pragma unroll
    for (int n = 0; n < 4; ++n) acc[m][n] = f32x4{0.f, 0.f, 0.f, 0.f};

  auto rdAH = [&](bf16x8* d, int p, int mh) {   // 4m x 2kk = 8 reads
#pragma unroll
    for (int m2 = 0; m2 < 4; ++m2) {
      d[m2 * 2 + 0] = rdA(p, aoff0, mh * 4 + m2);
      d[m2 * 2 + 1] = rdA(p, aoff1, mh * 4 + m2);
    }
  };
  auto rdBH = [&](bf16x8* d, int p, int nh) {   // 2n x 2kk = 4 reads
#pragma unroll
    for (int n2 = 0; n2 < 2; ++n2) {
      d[n2 * 2 + 0] = rdB(p, boff0, nh * 2 + n2);
      d[n2 * 2 + 1] = rdB(p, boff1, nh * 2 + n2);
    }
  };
  auto quad = [&](int mh, int nh, bf16x8* aH, bf16x8* bH) {  // 16 MFMA
    __builtin_amdgcn_s_setprio(1);
#pragma unroll
    for (int kk = 0; kk < 2; ++kk)
#pragma unroll
      for (int m2 = 0; m2 < 4; ++m2)
#pragma unroll
        for (int n2 = 0; n2 < 2; ++n2)
          acc[mh * 4 + m2][nh * 2 + n2] = __builtin_amdgcn_mfma_f32_16x16x32_bf16(
              aH[m2 * 2 + kk], bH[n2 * 2 + kk], acc[mh * 4 + m2][nh * 2 + n2], 0, 0, 0);
    __builtin_amdgcn_s_setprio(0);
  };

  // ---- prologue: tile0 (4 halves) + tile1 B halves; force tile0 ----
  stA(0, 0, 0); stA(0, 1, 0); stB(0, 0, 0); stB(0, 1, 0);
  stB(1, 0, 1); stB(1, 1, 1);
  WAITV(4);        // force tile0's 8 loads; tile1-B's 4 stay in flight
  BAR();
  // ---- P1_0: preload tile0 aH0/bH0; stage A(1,0,1) ----
  rdAH(aH0, 0, 0); rdBH(bH0, 0, 0);
  stA(1, 0, 1);
  BAR();

  for (int it = 0; it < NT / 2; ++it) {
    const int T = 2 * it;
    const int t2 = (T + 2 < NT) ? T + 2 : NT - 1;
    const int t3 = (T + 3 < NT) ? T + 3 : NT - 1;
    // ---------- P2: rd bH1(T); Q1(T); st A(1,1,T+1) ----------
    rdBH(bH1, 0, 1);
    quad(0, 0, aH0, bH0);
    stA(1, 1, T + 1);
    BAR();
    // ---------- P3: rd aH1(T); Q2(T); st B(0,0,T+2) ----------
    rdAH(aH1, 0, 1);
    quad(0, 1, aH0, bH1);
    stB(0, 0, t2);
    BAR();
    // ---------- P4: Q3(T); st B(0,1,T+2)+A(0,0,T+2); vmcnt(6) ----------
    quad(1, 1, aH1, bH1);
    stB(0, 1, t2); stA(0, 0, t2);
    WAITV(6);
    BAR();
    // ---------- P5: rd aH0(T+1); Q4(T); rd bH0(T+1); st A(0,1,T+2) ----------
    rdAH(aH0, 1, 0);
    quad(1, 0, aH1, bH0);
    rdBH(bH0, 1, 0);
    stA(0, 1, t2);
    BAR();
    // ---------- P6: rd bH1(T+1); Q1(T+1) ----------
    rdBH(bH1, 1, 1);
    quad(0, 0, aH0, bH0);
    BAR();
    // ---------- P7: rd aH1(T+1); Q2(T+1); st B(1,0,T+3) ----------
    rdAH(aH1, 1, 1);
    quad(0, 1, aH0, bH1);
    stB(1, 0, t3);
    BAR();
    // ---------- P8: Q3(T+1); st B(1,1,T+3); vmcnt(4) ----------
    quad(1, 1, aH1, bH1);
    stB(1, 1, t3);
    WAITV(4);
    BAR();
    // ---------- P1: rd aH0(T+2); Q4(T+1); rd bH0(T+2); st A(1,0,T+3) ----------
    rdAH(aH0, 0, 0);
    quad(1, 0, aH1, bH0);
    rdBH(bH0, 0, 0);
    stA(1, 0, t3);
    BAR();
  }
  WAITV(0);

  // ---- epilogue: bias + relu, fp32 stores ----
  const int row0 = bm * 256 + wr * 128;
  const int col0 = bn * 256 + wc * 64;
#pragma unroll
  for (int n = 0; n < 4; ++n) {
    const int col = col0 + n * 16 + lr;
    const float bv = bias[col];
#pragma unroll
    for (int m = 0; m < 8; ++m) {
      const int r0 = row0 + m * 16 + lk * 4;
#pragma unroll
      for (int vv = 0; vv < 4; ++vv) {
        const float val = acc[m][n][vv] + bv;
        C[(size_t)(r0 + vv) * N + col] = val > 0.f ? val : 0.f;
      }
    }
  }
}

extern "C" void kernel_launch(void* const* d_in, const int* in_sizes, int n_in,
                              void* d_out, int out_size, void* d_ws, size_t ws_size,
                              hipStream_t stream) {
  const float* x  = (const float*)d_in[0];
  const float* c0 = (const float*)d_in[1];
  const float* c1 = (const float*)d_in[2];
  const float* c2 = (const float*)d_in[3];
  const float* c3 = (const float*)d_in[4];
  const float* b  = (const float*)d_in[5];
  float* out = (float*)d_out;

  u16* xb  = (u16*)d_ws;                       // 32 MB bf16 x
  u16* mtb = xb + (size_t)4096 * 4096;         // 32 MB bf16 M^T

  prep_fused<<<dim3(4096 + 8192), dim3(256), 0, stream>>>(x, xb, c0, c1, c2, c3, mtb);
  gemm_bias_relu<<<dim3(16, 16), dim3(512), 0, stream>>>(xb, mtb, b, out);
}